// Round 19
// baseline (3156.862 us; speedup 1.0000x reference)
//
#include <hip/hip_runtime.h>
#include <hip/hip_bf16.h>
#include <cstdint>
#include <cstddef>

#define B_   64
#define T_   512
#define D_   512
#define H0_  1024
#define H1_  512
#define NGRP 4
#define BPG  64
#define NWORK 256    // 4 groups x 64 blocks, 1 block/CU, plain launch

typedef __attribute__((ext_vector_type(8))) short bf16x8;
typedef __attribute__((ext_vector_type(4))) float f32x4;
typedef unsigned long long u64;

// LDS: zp0 (64 rows x 68 f) 17,408 B @0 | zp1 (64 x 36 f) 9,216 B @17408
#define LDS_ZP0 0
#define LDS_ZP1 17408
#define LDS_BYTES 26624
#define ZROW0 68
#define ZROW1 36

__device__ __forceinline__ float sigmf(float x) {
    return __builtin_amdgcn_rcpf(1.0f + __expf(-x));
}
__device__ __forceinline__ float ftanh(float x) {
    float xc = fminf(fmaxf(x, -15.f), 15.f);
    float t = __expf(2.f * xc);
    return (t - 1.f) * __builtin_amdgcn_rcpf(t + 1.f);
}
__device__ __forceinline__ unsigned short bf16bits(float x) {
    union { __hip_bfloat16 h; unsigned short s; } u; u.h = __float2bfloat16(x); return u.s;
}
__device__ __forceinline__ u64 ald(const void* p) {
    return __hip_atomic_load((const u64*)p, __ATOMIC_RELAXED, __HIP_MEMORY_SCOPE_AGENT);
}

// ---------------------------------------------------------------------------
__global__ void mask_kernel(const float* __restrict__ x, unsigned char* __restrict__ mask) {
    int row  = blockIdx.x * 4 + (threadIdx.x >> 6);
    int lane = threadIdx.x & 63;
    const float4* p = reinterpret_cast<const float4*>(x + (size_t)row * D_) + lane * 2;
    float4 a = p[0], b = p[1];
    bool nz = (a.x != 0.f) | (a.y != 0.f) | (a.z != 0.f) | (a.w != 0.f)
            | (b.x != 0.f) | (b.y != 0.f) | (b.z != 0.f) | (b.w != 0.f);
    int m = __any(nz);
    if (lane == 0) mask[row] = m ? 1 : 0;
}

__global__ void xbf_kernel(const float* __restrict__ in, __hip_bfloat16* __restrict__ xbf) {
    int i  = blockIdx.x * 256 + threadIdx.x;
    int d8 = i & 63;
    int row = i >> 6;
    int b = row >> 9, t = row & 511;
    const float* src = in + (size_t)row * D_ + d8 * 8;
    __hip_bfloat16 o[8];
    #pragma unroll
    for (int j = 0; j < 8; ++j) o[j] = __float2bfloat16(src[j]);
    *reinterpret_cast<bf16x8*>(xbf + ((size_t)t * B_ + b) * D_ + d8 * 8) =
        *reinterpret_cast<bf16x8*>(o);
}

// ---------------------------------------------------------------------------
// R17 structure + per-WAVE arrive (2 barriers/phase) + fast sigm/tanh.
// 4 independent batch-group chains (16 batches), 64 blocks/group.
// Block owns 16 L0-units + 8 L1-units, M=16. All weights in VGPR frags.
// Phase p: PRE (mask + x_p*W0) pre-wait; wave0 polls 256 wave-flags
// (2 u64/lane) + acquire fence + barrier; MAIN: h1(p-2)->U1, h0(p-1)
// 4-deep pipeline -> U0 (4 nf) + W1 (2 nf), shared A-frags;
// zp dumps -> barrier -> gates0 (waves 0-1) || gates1 (wave 2) -> h stores
// (sc0sc1) -> per-wave vmcnt(0)+flag -> out store (off critical path).
// ---------------------------------------------------------------------------
__global__ __launch_bounds__(256, 1)
void lstm_persistent(const __hip_bfloat16* __restrict__ xbf,
    const float* __restrict__ W0, const float* __restrict__ U0,
    const float* __restrict__ W1, const float* __restrict__ U1,
    const float* __restrict__ b0, const float* __restrict__ b1,
    const unsigned char* __restrict__ mask,
    __hip_bfloat16* h0ring, __hip_bfloat16* h1ring, float* __restrict__ out,
    int* flags)
{
    __shared__ __align__(16) unsigned char smem[LDS_BYTES];
    const int bid = blockIdx.x;
    const int g   = bid >> 6;          // group (0..3)
    const int lb  = bid & 63;          // block within group
    const int tid = threadIdx.x;
    const int w = tid >> 6, lane = tid & 63;
    const int mr = lane & 15, kgrp = lane >> 4;
    const int ub0 = lb * 16, ub1 = lb * 8;
    const int brow = g * 16;           // batch row base
    int* gflags = flags + g * (BPG * 4);   // 256 wave-flags per group

    // ---- register frags (loop-invariant, statically indexed)
    bf16x8 bw0[4][4], bu0r[8][4], bw1r[8][2], bu1[4][2];
    {
        const int nn0 = lane & 15;
        #pragma unroll
        for (int c = 0; c < 4; ++c)
            #pragma unroll
            for (int nf = 0; nf < 4; ++nf) {
                int col = nf * 1024 + ub0 + nn0;              // gate=nf, unit=nn0
                int kb  = (w * 4 + c) * 32 + kgrp * 8;
                union { short s[8]; bf16x8 v; } t;
                #pragma unroll
                for (int j = 0; j < 8; ++j)
                    t.s[j] = (short)bf16bits(W0[(size_t)(kb + j) * 4096 + col]);
                bw0[c][nf] = t.v;
            }
        #pragma unroll
        for (int c = 0; c < 8; ++c)
            #pragma unroll
            for (int nf = 0; nf < 4; ++nf) {
                int col = nf * 1024 + ub0 + nn0;
                int kb  = (w * 8 + c) * 32 + kgrp * 8;
                union { short s[8]; bf16x8 v; } t;
                #pragma unroll
                for (int j = 0; j < 8; ++j)
                    t.s[j] = (short)bf16bits(U0[(size_t)(kb + j) * 4096 + col]);
                bu0r[c][nf] = t.v;
            }
        #pragma unroll
        for (int c = 0; c < 8; ++c)
            #pragma unroll
            for (int nf = 0; nf < 2; ++nf) {
                int nn  = nf * 16 + nn0;                      // gate=nn>>3, unit=nn&7
                int col = (nn >> 3) * 512 + ub1 + (nn & 7);
                int kb  = (w * 8 + c) * 32 + kgrp * 8;
                union { short s[8]; bf16x8 v; } t;
                #pragma unroll
                for (int j = 0; j < 8; ++j)
                    t.s[j] = (short)bf16bits(W1[(size_t)(kb + j) * 2048 + col]);
                bw1r[c][nf] = t.v;
            }
        #pragma unroll
        for (int c = 0; c < 4; ++c)
            #pragma unroll
            for (int nf = 0; nf < 2; ++nf) {
                int nn  = nf * 16 + nn0;
                int col = (nn >> 3) * 512 + ub1 + (nn & 7);
                int kb  = (w * 4 + c) * 32 + kgrp * 8;
                union { short s[8]; bf16x8 v; } t;
                #pragma unroll
                for (int j = 0; j < 8; ++j)
                    t.s[j] = (short)bf16bits(U1[(size_t)(kb + j) * 2048 + col]);
                bu1[c][nf] = t.v;
            }
    }

    // ---- gate-thread mappings (disjoint waves -> parallel gate phases)
    const bool g0t = (tid < 128);
    const bool g1t = (tid >= 128 && tid < 192);
    const int b0i = tid >> 3;
    const int up0 = (tid & 7) * 2;
    const int b1i = (tid - 128) >> 2;
    const int up1 = ((tid - 128) & 3) * 2;

    float h0reg[2] = {0.f, 0.f}, c0reg[2] = {0.f, 0.f}, br0[8];
    float h1reg[2] = {0.f, 0.f}, c1reg[2] = {0.f, 0.f}, br1[8];
    if (g0t) {
        #pragma unroll
        for (int gg = 0; gg < 4; ++gg) {
            br0[gg]     = b0[gg * H0_ + ub0 + up0];
            br0[4 + gg] = b0[gg * H0_ + ub0 + up0 + 1];
        }
    }
    if (g1t) {
        #pragma unroll
        for (int gg = 0; gg < 4; ++gg) {
            br1[gg]     = b1[gg * H1_ + ub1 + up1];
            br1[4 + gg] = b1[gg * H1_ + ub1 + up1 + 1];
        }
    }
    __syncthreads();

    float* zp0 = (float*)(smem + LDS_ZP0);
    float* zp1 = (float*)(smem + LDS_ZP1);

    #pragma unroll 1
    for (int p = 0; p <= T_; ++p) {
        const bool doL0 = (p < T_);
        const bool doL1 = (p >= 1);

        f32x4 acc0[4];
        f32x4 acc1[2];
        #pragma unroll
        for (int nf = 0; nf < 4; ++nf) { f32x4 z = {0.f,0.f,0.f,0.f}; acc0[nf] = z; }
        #pragma unroll
        for (int nf = 0; nf < 2; ++nf) { f32x4 z = {0.f,0.f,0.f,0.f}; acc1[nf] = z; }

        // ---- PRE: mask prefetch + z0 x-part (W0 reg frags; pre-wait)
        bool msk0 = false, msk1 = false;
        if (doL0 && g0t) msk0 = mask[(brow + b0i) * T_ + p] != 0;
        if (doL1 && g1t) msk1 = mask[(brow + b1i) * T_ + (p - 1)] != 0;
        if (doL0) {
            const __hip_bfloat16* xa = xbf + (size_t)p * (B_ * D_)
                                     + (size_t)(brow + mr) * D_ + kgrp * 8;
            #pragma unroll
            for (int c = 0; c < 4; ++c) {
                bf16x8 af = *(const bf16x8*)(xa + (w * 4 + c) * 32);
                #pragma unroll
                for (int nf = 0; nf < 4; ++nf)
                    acc0[nf] = __builtin_amdgcn_mfma_f32_16x16x32_bf16(af, bw0[c][nf], acc0[nf], 0, 0, 0);
            }
        }

        // ---- wait: wave0 polls own group's 256 wave-flags (2 u64/lane), fence, barrier
        if (p > 0) {
            if (tid < 64) {
                const u64* f = (const u64*)gflags + tid;
                for (;;) {
                    u64 a = ald(f);
                    u64 b = ald(f + 64);
                    bool ok = ((int)a >= p) && ((int)(a >> 32) >= p)
                           && ((int)b >= p) && ((int)(b >> 32) >= p);
                    if (__all(ok)) break;
                    __builtin_amdgcn_s_sleep(1);
                }
                __builtin_amdgcn_fence(__ATOMIC_ACQUIRE, "agent");
            }
            __syncthreads();
        }

        const __hip_bfloat16* h0r = h0ring + (size_t)((p + 1) & 1) * (B_ * H0_); // h0(p-1)
        const __hip_bfloat16* h1r = h1ring + (size_t)(p & 1) * (B_ * H1_);       // h1(p-2)

        // ---- h1 loads (plain cached; issued first)
        bf16x8 h1a[4];
        if (doL1) {
            const __hip_bfloat16* src = h1r + (size_t)(brow + mr) * H1_ + kgrp * 8;
            #pragma unroll
            for (int c = 0; c < 4; ++c)
                h1a[c] = *(const bf16x8*)(src + (w * 4 + c) * 32);
        }

        // ---- h0 pipeline: prologue 4 chunks
        const __hip_bfloat16* h0s = h0r + (size_t)(brow + mr) * H0_ + kgrp * 8;
        bf16x8 areg[4];
        #pragma unroll
        for (int c = 0; c < 4; ++c)
            areg[c] = *(const bf16x8*)(h0s + (w * 8 + c) * 32);

        // ---- consume h1 (U1 reg frags -> z1)
        if (doL1) {
            #pragma unroll
            for (int c = 0; c < 4; ++c)
                #pragma unroll
                for (int nf = 0; nf < 2; ++nf)
                    acc1[nf] = __builtin_amdgcn_mfma_f32_16x16x32_bf16(h1a[c], bu1[c][nf], acc1[nf], 0, 0, 0);
        }

        // ---- h0 loop: shared A-frags feed U0 (z0, 4 nf) and W1 (z1, 2 nf)
        #pragma unroll
        for (int c = 0; c < 8; ++c) {
            bf16x8 cur = areg[c & 3];
            if (c + 4 < 8) areg[c & 3] = *(const bf16x8*)(h0s + (w * 8 + c + 4) * 32);
            if (doL0) {
                #pragma unroll
                for (int nf = 0; nf < 4; ++nf)
                    acc0[nf] = __builtin_amdgcn_mfma_f32_16x16x32_bf16(cur, bu0r[c][nf], acc0[nf], 0, 0, 0);
            }
            if (doL1) {
                #pragma unroll
                for (int nf = 0; nf < 2; ++nf)
                    acc1[nf] = __builtin_amdgcn_mfma_f32_16x16x32_bf16(cur, bw1r[c][nf], acc1[nf], 0, 0, 0);
            }
        }

        // ---- dumps to disjoint LDS, ONE sync
        if (doL0) {
            #pragma unroll
            for (int nf = 0; nf < 4; ++nf)
                #pragma unroll
                for (int r = 0; r < 4; ++r)
                    zp0[(w * 16 + kgrp * 4 + r) * ZROW0 + nf * 16 + mr] = acc0[nf][r];
        }
        if (doL1) {
            #pragma unroll
            for (int nf = 0; nf < 2; ++nf)
                #pragma unroll
                for (int r = 0; r < 4; ++r)
                    zp1[(w * 16 + kgrp * 4 + r) * ZROW1 + nf * 16 + mr] = acc1[nf][r];
        }
        __syncthreads();

        // ---- gates0 (waves 0-1) PARALLEL gates1 (wave 2), then h stores
        if (doL0 && g0t) {
            float z[2][4];
            #pragma unroll
            for (int gg = 0; gg < 4; ++gg) {
                float sx = 0.f, sy = 0.f;
                #pragma unroll
                for (int wv = 0; wv < 4; ++wv) {
                    float2 s = *(const float2*)&zp0[(wv * 16 + b0i) * ZROW0 + gg * 16 + up0];
                    sx += s.x; sy += s.y;
                }
                z[0][gg] = sx + br0[gg];
                z[1][gg] = sy + br0[4 + gg];
            }
            #pragma unroll
            for (int i = 0; i < 2; ++i) {
                float ig = sigmf(z[i][0]), fg = sigmf(z[i][1]);
                float gv = ftanh(z[i][2]), og = sigmf(z[i][3]);
                float cn = fg * c0reg[i] + ig * gv;
                float hn = og * ftanh(cn);
                if (msk0) { c0reg[i] = cn; h0reg[i] = hn; }
            }
            __hip_bfloat16* h0w = h0ring + (size_t)(p & 1) * (B_ * H0_);
            union { unsigned short s[2]; unsigned u; } hv;
            hv.s[0] = bf16bits(h0reg[0]);
            hv.s[1] = bf16bits(h0reg[1]);
            __hip_atomic_store((unsigned*)&h0w[(size_t)(brow + b0i) * H0_ + ub0 + up0], hv.u,
                               __ATOMIC_RELAXED, __HIP_MEMORY_SCOPE_AGENT);
        }
        if (doL1 && g1t) {
            float z[2][4];
            #pragma unroll
            for (int gg = 0; gg < 4; ++gg) {
                float sx = 0.f, sy = 0.f;
                #pragma unroll
                for (int wv = 0; wv < 4; ++wv) {
                    float2 s = *(const float2*)&zp1[(wv * 16 + b1i) * ZROW1 + gg * 8 + up1];
                    sx += s.x; sy += s.y;
                }
                z[0][gg] = sx + br1[gg];
                z[1][gg] = sy + br1[4 + gg];
            }
            #pragma unroll
            for (int i = 0; i < 2; ++i) {
                float ig = sigmf(z[i][0]), fg = sigmf(z[i][1]);
                float gv = ftanh(z[i][2]), og = sigmf(z[i][3]);
                float cn = fg * c1reg[i] + ig * gv;
                float hn = og * ftanh(cn);
                if (msk1) { c1reg[i] = cn; h1reg[i] = hn; }
            }
            __hip_bfloat16* h1w = h1ring + (size_t)((p + 1) & 1) * (B_ * H1_); // slot (p-1)&1
            union { unsigned short s[2]; unsigned u; } hv;
            hv.s[0] = bf16bits(h1reg[0]);
            hv.s[1] = bf16bits(h1reg[1]);
            __hip_atomic_store((unsigned*)&h1w[(size_t)(brow + b1i) * H1_ + ub1 + up1], hv.u,
                               __ATOMIC_RELAXED, __HIP_MEMORY_SCOPE_AGENT);
        }

        // ---- per-WAVE arrive: drain own loads+stores, publish own wave flag
        if (p < T_) {
            asm volatile("s_waitcnt vmcnt(0)" ::: "memory");
            if (lane == 0)
                __hip_atomic_store(gflags + lb * 4 + w, p + 1,
                                   __ATOMIC_RELAXED, __HIP_MEMORY_SCOPE_AGENT);
        }

        // ---- out store AFTER flag publish (nobody reads out)
        if (doL1 && g1t) {
            const int t1 = p - 1;
            float2 ov; ov.x = h1reg[0]; ov.y = h1reg[1];
            *reinterpret_cast<float2*>(&out[((size_t)(brow + b1i) * T_ + t1) * H1_ + ub1 + up1]) = ov;
        }
    }
}

// ---------------------------------------------------------------------------
extern "C" void kernel_launch(void* const* d_in, const int* in_sizes, int n_in,
                              void* d_out, int out_size, void* d_ws, size_t ws_size,
                              hipStream_t stream)
{
    const float* inputs = (const float*)d_in[0];
    const float* W0     = (const float*)d_in[1];
    const float* U0     = (const float*)d_in[2];
    const float* b0     = (const float*)d_in[3];
    const float* W1     = (const float*)d_in[4];
    const float* U1     = (const float*)d_in[5];
    const float* b1     = (const float*)d_in[6];
    float* out = (float*)d_out;

    // ws (bf16 elems): xbf 16,777,216 | h0ring 131,072 | h1ring 65,536
    //                  | mask 32,768 B | flags 4,096 B  (~32.4 MiB)
    __hip_bfloat16* xbf    = (__hip_bfloat16*)d_ws;
    __hip_bfloat16* h0ring = xbf + 16777216;
    __hip_bfloat16* h1ring = h0ring + 131072;
    unsigned char*  mask   = (unsigned char*)(h1ring + 65536);
    int* flags = (int*)(mask + 32768);

    hipMemsetAsync(h0ring, 0, (131072 + 65536) * sizeof(__hip_bfloat16), stream);
    hipMemsetAsync(flags, 0, NGRP * BPG * 4 * sizeof(int), stream);
    mask_kernel<<<(B_ * T_) / 4, 256, 0, stream>>>(inputs, mask);
    xbf_kernel<<<(B_ * T_ * D_ / 8) / 256, 256, 0, stream>>>(inputs, xbf);

    lstm_persistent<<<dim3(NWORK), dim3(256), 0, stream>>>(
        xbf, W0, U0, W1, U1, b0, b1, mask, h0ring, h1ring, out, flags);
}

// Round 20
// 2960.886 us; speedup vs baseline: 1.0662x; 1.0662x over previous
//
#include <hip/hip_runtime.h>
#include <hip/hip_bf16.h>
#include <cstdint>
#include <cstddef>

#define B_   64
#define T_   512
#define D_   512
#define H0_  1024
#define H1_  512
#define NGRP 4
#define BPG  64
#define NWORK 256    // 4 groups x 64 blocks, 1 block/CU, plain launch

typedef __attribute__((ext_vector_type(8))) short bf16x8;
typedef __attribute__((ext_vector_type(4))) float f32x4;
typedef unsigned long long u64;

// LDS: zp0 (64 rows x 68 f) 17,408 B @0 | zp1 (64 x 36 f) 9,216 B @17408
#define LDS_ZP0 0
#define LDS_ZP1 17408
#define LDS_BYTES 26624
#define ZROW0 68
#define ZROW1 36

__device__ __forceinline__ float sigmf(float x) {
    return __builtin_amdgcn_rcpf(1.0f + __expf(-x));
}
__device__ __forceinline__ float ftanh(float x) {
    float xc = fminf(fmaxf(x, -15.f), 15.f);
    float t = __expf(2.f * xc);
    return (t - 1.f) * __builtin_amdgcn_rcpf(t + 1.f);
}
__device__ __forceinline__ unsigned short bf16bits(float x) {
    union { __hip_bfloat16 h; unsigned short s; } u; u.h = __float2bfloat16(x); return u.s;
}

// ---------------------------------------------------------------------------
__global__ void mask_kernel(const float* __restrict__ x, unsigned char* __restrict__ mask) {
    int row  = blockIdx.x * 4 + (threadIdx.x >> 6);
    int lane = threadIdx.x & 63;
    const float4* p = reinterpret_cast<const float4*>(x + (size_t)row * D_) + lane * 2;
    float4 a = p[0], b = p[1];
    bool nz = (a.x != 0.f) | (a.y != 0.f) | (a.z != 0.f) | (a.w != 0.f)
            | (b.x != 0.f) | (b.y != 0.f) | (b.z != 0.f) | (b.w != 0.f);
    int m = __any(nz);
    if (lane == 0) mask[row] = m ? 1 : 0;
}

__global__ void xbf_kernel(const float* __restrict__ in, __hip_bfloat16* __restrict__ xbf) {
    int i  = blockIdx.x * 256 + threadIdx.x;
    int d8 = i & 63;
    int row = i >> 6;
    int b = row >> 9, t = row & 511;
    const float* src = in + (size_t)row * D_ + d8 * 8;
    __hip_bfloat16 o[8];
    #pragma unroll
    for (int j = 0; j < 8; ++j) o[j] = __float2bfloat16(src[j]);
    *reinterpret_cast<bf16x8*>(xbf + ((size_t)t * B_ + b) * D_ + d8 * 8) =
        *reinterpret_cast<bf16x8*>(o);
}

// ---------------------------------------------------------------------------
// R17 structure exactly (block arrive, 64-int poll) + fast sigm/tanh only.
// 4 independent batch-group chains (16 batches each), 64 blocks/group.
// Block owns 16 L0-units + 8 L1-units, M=16 (single m-tile), weights in VGPRs.
// ---------------------------------------------------------------------------
__global__ __launch_bounds__(256, 1)
void lstm_persistent(const __hip_bfloat16* __restrict__ xbf,
    const float* __restrict__ W0, const float* __restrict__ U0,
    const float* __restrict__ W1, const float* __restrict__ U1,
    const float* __restrict__ b0, const float* __restrict__ b1,
    const unsigned char* __restrict__ mask,
    __hip_bfloat16* h0ring, __hip_bfloat16* h1ring, float* __restrict__ out,
    int* flags)
{
    __shared__ __align__(16) unsigned char smem[LDS_BYTES];
    const int bid = blockIdx.x;
    const int g   = bid >> 6;          // group (0..3)
    const int lb  = bid & 63;          // block within group
    const int tid = threadIdx.x;
    const int w = tid >> 6, lane = tid & 63;
    const int mr = lane & 15, kgrp = lane >> 4;
    const int ub0 = lb * 16, ub1 = lb * 8;
    const int brow = g * 16;           // batch row base
    int* gflags = flags + g * BPG;

    // ---- register frags (loop-invariant, statically indexed)
    bf16x8 bw0[4][4], bu0r[8][4], bw1r[8][2], bu1[4][2];
    {
        const int nn0 = lane & 15;
        #pragma unroll
        for (int c = 0; c < 4; ++c)
            #pragma unroll
            for (int nf = 0; nf < 4; ++nf) {
                int col = nf * 1024 + ub0 + nn0;              // gate=nf, unit=nn0
                int kb  = (w * 4 + c) * 32 + kgrp * 8;
                union { short s[8]; bf16x8 v; } t;
                #pragma unroll
                for (int j = 0; j < 8; ++j)
                    t.s[j] = (short)bf16bits(W0[(size_t)(kb + j) * 4096 + col]);
                bw0[c][nf] = t.v;
            }
        #pragma unroll
        for (int c = 0; c < 8; ++c)
            #pragma unroll
            for (int nf = 0; nf < 4; ++nf) {
                int col = nf * 1024 + ub0 + nn0;
                int kb  = (w * 8 + c) * 32 + kgrp * 8;
                union { short s[8]; bf16x8 v; } t;
                #pragma unroll
                for (int j = 0; j < 8; ++j)
                    t.s[j] = (short)bf16bits(U0[(size_t)(kb + j) * 4096 + col]);
                bu0r[c][nf] = t.v;
            }
        #pragma unroll
        for (int c = 0; c < 8; ++c)
            #pragma unroll
            for (int nf = 0; nf < 2; ++nf) {
                int nn  = nf * 16 + nn0;                      // gate=nn>>3, unit=nn&7
                int col = (nn >> 3) * 512 + ub1 + (nn & 7);
                int kb  = (w * 8 + c) * 32 + kgrp * 8;
                union { short s[8]; bf16x8 v; } t;
                #pragma unroll
                for (int j = 0; j < 8; ++j)
                    t.s[j] = (short)bf16bits(W1[(size_t)(kb + j) * 2048 + col]);
                bw1r[c][nf] = t.v;
            }
        #pragma unroll
        for (int c = 0; c < 4; ++c)
            #pragma unroll
            for (int nf = 0; nf < 2; ++nf) {
                int nn  = nf * 16 + nn0;
                int col = (nn >> 3) * 512 + ub1 + (nn & 7);
                int kb  = (w * 4 + c) * 32 + kgrp * 8;
                union { short s[8]; bf16x8 v; } t;
                #pragma unroll
                for (int j = 0; j < 8; ++j)
                    t.s[j] = (short)bf16bits(U1[(size_t)(kb + j) * 2048 + col]);
                bu1[c][nf] = t.v;
            }
    }

    // ---- gate-thread mappings (disjoint waves -> parallel gate phases)
    const bool g0t = (tid < 128);
    const bool g1t = (tid >= 128 && tid < 192);
    const int b0i = tid >> 3;
    const int up0 = (tid & 7) * 2;
    const int b1i = (tid - 128) >> 2;
    const int up1 = ((tid - 128) & 3) * 2;

    float h0reg[2] = {0.f, 0.f}, c0reg[2] = {0.f, 0.f}, br0[8];
    float h1reg[2] = {0.f, 0.f}, c1reg[2] = {0.f, 0.f}, br1[8];
    if (g0t) {
        #pragma unroll
        for (int gg = 0; gg < 4; ++gg) {
            br0[gg]     = b0[gg * H0_ + ub0 + up0];
            br0[4 + gg] = b0[gg * H0_ + ub0 + up0 + 1];
        }
    }
    if (g1t) {
        #pragma unroll
        for (int gg = 0; gg < 4; ++gg) {
            br1[gg]     = b1[gg * H1_ + ub1 + up1];
            br1[4 + gg] = b1[gg * H1_ + ub1 + up1 + 1];
        }
    }
    __syncthreads();

    float* zp0 = (float*)(smem + LDS_ZP0);
    float* zp1 = (float*)(smem + LDS_ZP1);

    #pragma unroll 1
    for (int p = 0; p <= T_; ++p) {
        const bool doL0 = (p < T_);
        const bool doL1 = (p >= 1);

        f32x4 acc0[4];
        f32x4 acc1[2];
        #pragma unroll
        for (int nf = 0; nf < 4; ++nf) { f32x4 z = {0.f,0.f,0.f,0.f}; acc0[nf] = z; }
        #pragma unroll
        for (int nf = 0; nf < 2; ++nf) { f32x4 z = {0.f,0.f,0.f,0.f}; acc1[nf] = z; }

        // ---- PRE: mask prefetch + z0 x-part (W0 reg frags; pre-wait)
        bool msk0 = false, msk1 = false;
        if (doL0 && g0t) msk0 = mask[(brow + b0i) * T_ + p] != 0;
        if (doL1 && g1t) msk1 = mask[(brow + b1i) * T_ + (p - 1)] != 0;
        if (doL0) {
            const __hip_bfloat16* xa = xbf + (size_t)p * (B_ * D_)
                                     + (size_t)(brow + mr) * D_ + kgrp * 8;
            #pragma unroll
            for (int c = 0; c < 4; ++c) {
                bf16x8 af = *(const bf16x8*)(xa + (w * 4 + c) * 32);
                #pragma unroll
                for (int nf = 0; nf < 4; ++nf)
                    acc0[nf] = __builtin_amdgcn_mfma_f32_16x16x32_bf16(af, bw0[c][nf], acc0[nf], 0, 0, 0);
            }
        }

        // ---- wait: wave0 polls own group's 64 int flags (1/lane), fence, barrier
        if (p > 0) {
            if (tid < 64) {
                for (;;) {
                    int a = __hip_atomic_load(gflags + tid, __ATOMIC_RELAXED, __HIP_MEMORY_SCOPE_AGENT);
                    if (__all(a >= p)) break;
                    __builtin_amdgcn_s_sleep(1);
                }
                __builtin_amdgcn_fence(__ATOMIC_ACQUIRE, "agent");
            }
            __syncthreads();
        }

        const __hip_bfloat16* h0r = h0ring + (size_t)((p + 1) & 1) * (B_ * H0_); // h0(p-1)
        const __hip_bfloat16* h1r = h1ring + (size_t)(p & 1) * (B_ * H1_);       // h1(p-2)

        // ---- h1 loads (plain cached; issued first)
        bf16x8 h1a[4];
        if (doL1) {
            const __hip_bfloat16* src = h1r + (size_t)(brow + mr) * H1_ + kgrp * 8;
            #pragma unroll
            for (int c = 0; c < 4; ++c)
                h1a[c] = *(const bf16x8*)(src + (w * 4 + c) * 32);
        }

        // ---- h0 pipeline: prologue 4 chunks
        const __hip_bfloat16* h0s = h0r + (size_t)(brow + mr) * H0_ + kgrp * 8;
        bf16x8 areg[4];
        #pragma unroll
        for (int c = 0; c < 4; ++c)
            areg[c] = *(const bf16x8*)(h0s + (w * 8 + c) * 32);

        // ---- consume h1 (U1 reg frags -> z1)
        if (doL1) {
            #pragma unroll
            for (int c = 0; c < 4; ++c)
                #pragma unroll
                for (int nf = 0; nf < 2; ++nf)
                    acc1[nf] = __builtin_amdgcn_mfma_f32_16x16x32_bf16(h1a[c], bu1[c][nf], acc1[nf], 0, 0, 0);
        }

        // ---- h0 loop: shared A-frags feed U0 (z0, 4 nf) and W1 (z1, 2 nf)
        #pragma unroll
        for (int c = 0; c < 8; ++c) {
            bf16x8 cur = areg[c & 3];
            if (c + 4 < 8) areg[c & 3] = *(const bf16x8*)(h0s + (w * 8 + c + 4) * 32);
            if (doL0) {
                #pragma unroll
                for (int nf = 0; nf < 4; ++nf)
                    acc0[nf] = __builtin_amdgcn_mfma_f32_16x16x32_bf16(cur, bu0r[c][nf], acc0[nf], 0, 0, 0);
            }
            if (doL1) {
                #pragma unroll
                for (int nf = 0; nf < 2; ++nf)
                    acc1[nf] = __builtin_amdgcn_mfma_f32_16x16x32_bf16(cur, bw1r[c][nf], acc1[nf], 0, 0, 0);
            }
        }

        // ---- dumps to disjoint LDS, ONE sync
        if (doL0) {
            #pragma unroll
            for (int nf = 0; nf < 4; ++nf)
                #pragma unroll
                for (int r = 0; r < 4; ++r)
                    zp0[(w * 16 + kgrp * 4 + r) * ZROW0 + nf * 16 + mr] = acc0[nf][r];
        }
        if (doL1) {
            #pragma unroll
            for (int nf = 0; nf < 2; ++nf)
                #pragma unroll
                for (int r = 0; r < 4; ++r)
                    zp1[(w * 16 + kgrp * 4 + r) * ZROW1 + nf * 16 + mr] = acc1[nf][r];
        }
        __syncthreads();

        // ---- gates0 (waves 0-1) PARALLEL gates1 (wave 2), then h stores
        if (doL0 && g0t) {
            float z[2][4];
            #pragma unroll
            for (int gg = 0; gg < 4; ++gg) {
                float sx = 0.f, sy = 0.f;
                #pragma unroll
                for (int wv = 0; wv < 4; ++wv) {
                    float2 s = *(const float2*)&zp0[(wv * 16 + b0i) * ZROW0 + gg * 16 + up0];
                    sx += s.x; sy += s.y;
                }
                z[0][gg] = sx + br0[gg];
                z[1][gg] = sy + br0[4 + gg];
            }
            #pragma unroll
            for (int i = 0; i < 2; ++i) {
                float ig = sigmf(z[i][0]), fg = sigmf(z[i][1]);
                float gv = ftanh(z[i][2]), og = sigmf(z[i][3]);
                float cn = fg * c0reg[i] + ig * gv;
                float hn = og * ftanh(cn);
                if (msk0) { c0reg[i] = cn; h0reg[i] = hn; }
            }
            __hip_bfloat16* h0w = h0ring + (size_t)(p & 1) * (B_ * H0_);
            union { unsigned short s[2]; unsigned u; } hv;
            hv.s[0] = bf16bits(h0reg[0]);
            hv.s[1] = bf16bits(h0reg[1]);
            __hip_atomic_store((unsigned*)&h0w[(size_t)(brow + b0i) * H0_ + ub0 + up0], hv.u,
                               __ATOMIC_RELAXED, __HIP_MEMORY_SCOPE_AGENT);
        }
        if (doL1 && g1t) {
            float z[2][4];
            #pragma unroll
            for (int gg = 0; gg < 4; ++gg) {
                float sx = 0.f, sy = 0.f;
                #pragma unroll
                for (int wv = 0; wv < 4; ++wv) {
                    float2 s = *(const float2*)&zp1[(wv * 16 + b1i) * ZROW1 + gg * 8 + up1];
                    sx += s.x; sy += s.y;
                }
                z[0][gg] = sx + br1[gg];
                z[1][gg] = sy + br1[4 + gg];
            }
            #pragma unroll
            for (int i = 0; i < 2; ++i) {
                float ig = sigmf(z[i][0]), fg = sigmf(z[i][1]);
                float gv = ftanh(z[i][2]), og = sigmf(z[i][3]);
                float cn = fg * c1reg[i] + ig * gv;
                float hn = og * ftanh(cn);
                if (msk1) { c1reg[i] = cn; h1reg[i] = hn; }
            }
            __hip_bfloat16* h1w = h1ring + (size_t)((p + 1) & 1) * (B_ * H1_); // slot (p-1)&1
            union { unsigned short s[2]; unsigned u; } hv;
            hv.s[0] = bf16bits(h1reg[0]);
            hv.s[1] = bf16bits(h1reg[1]);
            __hip_atomic_store((unsigned*)&h1w[(size_t)(brow + b1i) * H1_ + ub1 + up1], hv.u,
                               __ATOMIC_RELAXED, __HIP_MEMORY_SCOPE_AGENT);
        }

        // ---- drain h stores (vmcnt0 inside barrier), publish flag
        __syncthreads();
        if (p < T_ && tid == 0)
            __hip_atomic_store(gflags + lb, p + 1,
                               __ATOMIC_RELAXED, __HIP_MEMORY_SCOPE_AGENT);

        // ---- out store AFTER flag publish (nobody reads out)
        if (doL1 && g1t) {
            const int t1 = p - 1;
            float2 ov; ov.x = h1reg[0]; ov.y = h1reg[1];
            *reinterpret_cast<float2*>(&out[((size_t)(brow + b1i) * T_ + t1) * H1_ + ub1 + up1]) = ov;
        }
    }
}

// ---------------------------------------------------------------------------
extern "C" void kernel_launch(void* const* d_in, const int* in_sizes, int n_in,
                              void* d_out, int out_size, void* d_ws, size_t ws_size,
                              hipStream_t stream)
{
    const float* inputs = (const float*)d_in[0];
    const float* W0     = (const float*)d_in[1];
    const float* U0     = (const float*)d_in[2];
    const float* b0     = (const float*)d_in[3];
    const float* W1     = (const float*)d_in[4];
    const float* U1     = (const float*)d_in[5];
    const float* b1     = (const float*)d_in[6];
    float* out = (float*)d_out;

    // ws (bf16 elems): xbf 16,777,216 | h0ring 131,072 | h1ring 65,536
    //                  | mask 32,768 B | flags 1,024 B  (~32.4 MiB)
    __hip_bfloat16* xbf    = (__hip_bfloat16*)d_ws;
    __hip_bfloat16* h0ring = xbf + 16777216;
    __hip_bfloat16* h1ring = h0ring + 131072;
    unsigned char*  mask   = (unsigned char*)(h1ring + 65536);
    int* flags = (int*)(mask + 32768);

    hipMemsetAsync(h0ring, 0, (131072 + 65536) * sizeof(__hip_bfloat16), stream);
    hipMemsetAsync(flags, 0, NWORK * sizeof(int), stream);
    mask_kernel<<<(B_ * T_) / 4, 256, 0, stream>>>(inputs, mask);
    xbf_kernel<<<(B_ * T_ * D_ / 8) / 256, 256, 0, stream>>>(inputs, xbf);

    lstm_persistent<<<dim3(NWORK), dim3(256), 0, stream>>>(
        xbf, W0, U0, W1, U1, b0, b1, mask, h0ring, h1ring, out, flags);
}